// Round 5
// baseline (210.261 us; speedup 1.0000x reference)
//
#include <hip/hip_runtime.h>
#include <stdint.h>

// Problem constants (fixed by the reference)
#define H 56
#define W 56
#define HW (H * W)          // 3136
#define CIN 256
#define IMG (CIN * HW)      // 802816 elements per image
#define EPS 1e-5f

#define ROWW 8              // u32 words per tile row: 32B = 64 nibbles
#define WROWS 16            // tile rows per wave: 14 output + 2 halo

// Strict fp32 RN ops, immune to -ffp-contract (inline asm cannot be fused).
// Round 3 proved the np reference's exact-zero BN outputs (sign->0) only
// reproduce with the two-rounding chain round(round(x*inv)+bias).
__device__ __forceinline__ float mul_rn(float a, float b) {
    float d; asm("v_mul_f32 %0, %1, %2" : "=v"(d) : "v"(a), "v"(b)); return d;
}
__device__ __forceinline__ float add_rn(float a, float b) {
    float d; asm("v_add_f32 %0, %1, %2" : "=v"(d) : "v"(a), "v"(b)); return d;
}
__device__ __forceinline__ float sub_rn(float a, float b) {
    float d; asm("v_sub_f32 %0, %1, %2" : "=v"(d) : "v"(a), "v"(b)); return d;
}

// ---------------------------------------------------------------------------
// Fused BN -> ternary sign -> XNOR-popcount grouped 3x3 conv -> shuffle -> +x
// BARRIER-FREE: one row-quarter tile per WAVE (private LDS slice); intra-wave
// LDS ordering via s_waitcnt lgkmcnt(0) only. 4 waves/block share (n,g)
// (q = wave id) so channel planes are L1-reused; waves drift independently,
// mixing the read / L3-read / write streams instead of phase-locking them.
// ---------------------------------------------------------------------------
__global__ __launch_bounds__(256)
void binconv_kernel(const float* __restrict__ X,
                    const float* __restrict__ Wt,
                    const float* __restrict__ gamma,
                    const float* __restrict__ beta,
                    const float* __restrict__ mean,
                    const float* __restrict__ var,
                    float* __restrict__ out) {
    __shared__ uint32_t s_tiles[4][WROWS * ROWW];   // sign nibbles, per wave
    __shared__ uint32_t z_tiles[4][WROWS * ROWW];   // nonzero nibbles, per wave

    const int wid  = threadIdx.x >> 6;
    const int lane = threadIdx.x & 63;
    const int tile = blockIdx.x * 4 + wid;          // global wave-tile id
    const int q    = tile & 3;                      // row quarter 0..3
    const int g    = (tile >> 2) & 63;              // group
    const int n    = tile >> 8;                     // image
    const int row0 = q * 14 - 1;                    // input row of tile row 0

    uint32_t* st = s_tiles[wid];
    uint32_t* zt = z_tiles[wid];

    // Weights: lanes 0..11 each pack one (filter j, kernel row r) 12-bit
    // pattern pair (bit = kw*4 + ci), then broadcast via shuffle.
    uint32_t spat = 0, zpat = 0;
    if (lane < 12) {
        int j = lane / 3, r = lane - j * 3;
        const float* wc = Wt + (size_t)(g * 4 + j) * 36;   // [ci][kh][kw]
#pragma unroll
        for (int ci = 0; ci < 4; ++ci)
#pragma unroll
            for (int kw = 0; kw < 3; ++kw) {
                float v = wc[ci * 9 + r * 3 + kw];
                int b = kw * 4 + ci;
                spat |= (v > 0.f  ? 1u : 0u) << b;
                zpat |= (v != 0.f ? 1u : 0u) << b;
            }
    }
    uint32_t wsj[4][3], wzj[4][3];
    bool full = true;
#pragma unroll
    for (int j = 0; j < 4; ++j)
#pragma unroll
        for (int r = 0; r < 3; ++r) {
            wsj[j][r] = __shfl(spat, j * 3 + r, 64);
            wzj[j][r] = __shfl(zpat, j * 3 + r, 64);
            full = full && (wzj[j][r] == 0xFFFu);
        }

    // BN constants (strict np fp32 chain — see round-3 notes).
    float inv[4], bias[4];
#pragma unroll
    for (int ci = 0; ci < 4; ++ci) {
        int c = g * 4 + ci;
        float s  = sqrtf(var[c] + EPS);   // correctly rounded
        float r  = 1.0f / s;              // correctly rounded
        float iv = mul_rn(gamma[c], r);
        inv[ci]  = iv;
        bias[ci] = sub_rn(beta[c], mul_rn(mean[c], iv));
    }

    // Zero word 7 of each tile row (nibble cols 56..63 = right padding).
    if (lane < WROWS) { st[lane * ROWW + 7] = 0u; zt[lane * ROWW + 7] = 0u; }

    const float* Xn = X + (size_t)n * IMG;

    // Phase A: 16 rows x 14 col-groups; float4 loads, b16 LDS writes.
    // Rows outside the image (q=0 top halo, q=3 bottom halo) stay zero.
    for (int t = lane; t < WROWS * 14; t += 64) {
        int r  = t / 14;
        int cg = t - r * 14;
        int gr = row0 + r;
        uint32_t s16 = 0, z16 = 0;
        if ((unsigned)gr < (unsigned)H) {
            int off = gr * W + cg * 4;
#pragma unroll
            for (int ci = 0; ci < 4; ++ci) {
                const float4 v = *reinterpret_cast<const float4*>(
                    Xn + (size_t)(g * 4 + ci) * HW + off);
                float t0 = add_rn(mul_rn(v.x, inv[ci]), bias[ci]);
                float t1 = add_rn(mul_rn(v.y, inv[ci]), bias[ci]);
                float t2 = add_rn(mul_rn(v.z, inv[ci]), bias[ci]);
                float t3 = add_rn(mul_rn(v.w, inv[ci]), bias[ci]);
                s16 |= ((t0 > 0.f ? 1u : 0u) << ci)        | ((t1 > 0.f ? 1u : 0u) << (4 + ci))
                     | ((t2 > 0.f ? 1u : 0u) << (8 + ci))  | ((t3 > 0.f ? 1u : 0u) << (12 + ci));
            z16 |= ((t0 != 0.f ? 1u : 0u) << ci)       | ((t1 != 0.f ? 1u : 0u) << (4 + ci))
                 | ((t2 != 0.f ? 1u : 0u) << (8 + ci)) | ((t3 != 0.f ? 1u : 0u) << (12 + ci));
            }
        }
        reinterpret_cast<uint16_t*>(&st[r * ROWW])[cg] = (uint16_t)s16;
        reinterpret_cast<uint16_t*>(&zt[r * ROWW])[cg] = (uint16_t)z16;
    }

    // Wave-level producer->consumer sync: drain LDS ops; lockstep wave64
    // makes this sufficient (no s_barrier, so waves stay desynchronized).
    asm volatile("s_waitcnt lgkmcnt(0)" ::: "memory");

    float* On = out + (size_t)n * IMG;

    // Phase B: 14 output rows x 14 col-groups; tile rows h..h+2.
    for (int t = lane; t < 14 * 14; t += 64) {
        int h  = t / 14;
        int cg = t - h * 14;
        int w0 = cg * 4;

        uint64_t vs[3], vz[3];
        int off;
        if (cg == 0) {
            off = 0;
#pragma unroll
            for (int r = 0; r < 3; ++r) {
                int base = (h + r) * ROWW;
                vs[r] = (((uint64_t)st[base] | ((uint64_t)st[base + 1] << 32)) << 4);
                vz[r] = (((uint64_t)zt[base] | ((uint64_t)zt[base + 1] << 32)) << 4);
            }
        } else {
            int stb = 4 * w0 - 4;
            int i0  = stb >> 5;
            off     = stb & 31;
#pragma unroll
            for (int r = 0; r < 3; ++r) {
                int base = (h + r) * ROWW + i0;
                vs[r] = ((uint64_t)st[base] | ((uint64_t)st[base + 1] << 32));
                vz[r] = ((uint64_t)zt[base] | ((uint64_t)zt[base + 1] << 32));
            }
        }

        int res[4][4];
        if (full) {
#pragma unroll
            for (int k = 0; k < 4; ++k) {
                int sh = off + 4 * k;
                uint32_t s0 = (uint32_t)(vs[0] >> sh) & 0xFFFu;
                uint32_t s1 = (uint32_t)(vs[1] >> sh) & 0xFFFu;
                uint32_t s2 = (uint32_t)(vs[2] >> sh) & 0xFFFu;
                uint32_t z0 = (uint32_t)(vz[0] >> sh) & 0xFFFu;
                uint32_t z1 = (uint32_t)(vz[1] >> sh) & 0xFFFu;
                uint32_t z2 = (uint32_t)(vz[2] >> sh) & 0xFFFu;
                int vb = __popc(z0) + __popc(z1) + __popc(z2);
#pragma unroll
                for (int j = 0; j < 4; ++j) {
                    int pc = __popc((s0 ^ wsj[j][0]) & z0)
                           + __popc((s1 ^ wsj[j][1]) & z1)
                           + __popc((s2 ^ wsj[j][2]) & z2);
                    res[j][k] = vb - 2 * pc;
                }
            }
        } else {
#pragma unroll
            for (int k = 0; k < 4; ++k) {
                int sh = off + 4 * k;
                uint32_t s0 = (uint32_t)(vs[0] >> sh) & 0xFFFu;
                uint32_t s1 = (uint32_t)(vs[1] >> sh) & 0xFFFu;
                uint32_t s2 = (uint32_t)(vs[2] >> sh) & 0xFFFu;
                uint32_t z0 = (uint32_t)(vz[0] >> sh) & 0xFFFu;
                uint32_t z1 = (uint32_t)(vz[1] >> sh) & 0xFFFu;
                uint32_t z2 = (uint32_t)(vz[2] >> sh) & 0xFFFu;
#pragma unroll
                for (int j = 0; j < 4; ++j) {
                    uint32_t m0 = z0 & wzj[j][0];
                    uint32_t m1 = z1 & wzj[j][1];
                    uint32_t m2 = z2 & wzj[j][2];
                    int vb = __popc(m0) + __popc(m1) + __popc(m2);
                    int pc = __popc((s0 ^ wsj[j][0]) & m0)
                           + __popc((s1 ^ wsj[j][1]) & m1)
                           + __popc((s2 ^ wsj[j][2]) & m2);
                    res[j][k] = vb - 2 * pc;
                }
            }
        }

        // Epilogue: shuffled channel c' = j*64 + g; float4 shortcut + store.
        size_t pbase = (size_t)(q * 14 + h) * W + w0;
#pragma unroll
        for (int j = 0; j < 4; ++j) {
            size_t cofs = (size_t)(j * 64 + g) * HW + pbase;
            const float4 sc = *reinterpret_cast<const float4*>(Xn + cofs);
            float4 o;
            o.x = add_rn((float)res[j][0], sc.x);
            o.y = add_rn((float)res[j][1], sc.y);
            o.z = add_rn((float)res[j][2], sc.z);
            o.w = add_rn((float)res[j][3], sc.w);
            *reinterpret_cast<float4*>(On + cofs) = o;
        }
    }
}

// ---------------------------------------------------------------------------
extern "C" void kernel_launch(void* const* d_in, const int* in_sizes, int n_in,
                              void* d_out, int out_size, void* d_ws, size_t ws_size,
                              hipStream_t stream) {
    const float* X     = (const float*)d_in[0];
    const float* Wt    = (const float*)d_in[1];
    const float* gamma = (const float*)d_in[2];
    const float* beta  = (const float*)d_in[3];
    const float* mean  = (const float*)d_in[4];
    const float* var   = (const float*)d_in[5];
    float* out = (float*)d_out;

    int N = in_sizes[0] / IMG;        // 32

    // N*64 blocks x 4 waves; each wave owns one (n, g, row-quarter) tile.
    binconv_kernel<<<N * 64, 256, 0, stream>>>(X, Wt, gamma, beta, mean, var, out);
}